// Round 1
// baseline (1436.617 us; speedup 1.0000x reference)
//
#include <hip/hip_runtime.h>
#include <math.h>

#define NT 256

// ---------------- utility kernels ----------------

__global__ void zero_f32(float* __restrict__ p, int n) {
    int t = blockIdx.x * blockDim.x + threadIdx.x;
    int stride = gridDim.x * blockDim.x;
    for (int i = t; i < n; i += stride) p[i] = 0.0f;
}

__global__ void deg_count(float* __restrict__ deg, const int* __restrict__ dst, int n_edges) {
    int t = blockIdx.x * blockDim.x + threadIdx.x;
    int stride = gridDim.x * blockDim.x;
    for (int e = t; e < n_edges; e += stride)
        atomicAdd(&deg[dst[e]], 1.0f);
}

__global__ void deg_inv(float* __restrict__ deg, int n) {
    int t = blockIdx.x * blockDim.x + threadIdx.x;
    if (t < n) deg[t] = 1.0f / fmaxf(deg[t], 1.0f);
}

// ---------------- aggregation: scatter-add over edges ----------------
// wave per edge; lane = feature. Gather h[src] (coalesced 256B), atomicAdd into agg[dst].
__global__ void scatter_add(float* __restrict__ agg, const float* __restrict__ h,
                            const int* __restrict__ src, const int* __restrict__ dst,
                            int n_edges) {
    int lane = threadIdx.x & 63;
    int wave = (blockIdx.x * blockDim.x + threadIdx.x) >> 6;
    int nwaves = (gridDim.x * blockDim.x) >> 6;
    for (int e = wave; e < n_edges; e += nwaves) {
        int s = src[e];
        int d = dst[e];
        float v = h[(size_t)s * 64 + lane];
        atomicAdd(&agg[(size_t)d * 64 + lane], v);
    }
}

// ---------------- SAGE update (in-place on agg buffer) ----------------
// h_io holds agg on entry; h_in is the layer input.
// out[i][f] = tanh( (agg[i]*invdeg[i]) . Wl[f,:] + bl[f] + h_in[i] . Wr[f,:] )
__global__ void sage_update(float* __restrict__ h_io, const float* __restrict__ h_in,
                            const float* __restrict__ Wl, const float* __restrict__ Wr,
                            const float* __restrict__ bl, const float* __restrict__ invdeg,
                            int n_nodes) {
    __shared__ float WlT[64][64];  // WlT[k][f] = Wl[f][k]
    __shared__ float WrT[64][64];
    int tid = threadIdx.x;
    for (int t = tid; t < 4096; t += blockDim.x) {
        int f = t >> 6, k = t & 63;
        WlT[k][f] = Wl[t];
        WrT[k][f] = Wr[t];
    }
    __syncthreads();

    int lane = tid & 63;
    int wave = (blockIdx.x * blockDim.x + tid) >> 6;
    int nwaves = (gridDim.x * blockDim.x) >> 6;
    float bias = bl[lane];
    for (int i = wave; i < n_nodes; i += nwaves) {
        float m  = h_io[(size_t)i * 64 + lane] * invdeg[i];
        float hv = h_in[(size_t)i * 64 + lane];
        float acc = bias;
#pragma unroll
        for (int k = 0; k < 64; ++k) {
            float mk = __shfl(m, k);
            float hk = __shfl(hv, k);
            acc += mk * WlT[k][lane] + hk * WrT[k][lane];
        }
        h_io[(size_t)i * 64 + lane] = tanhf(acc);
    }
}

// ---------------- segment max pooling ----------------

__global__ void pool_init(float* __restrict__ pooled, int n) {
    int t = blockIdx.x * blockDim.x + threadIdx.x;
    if (t < n) pooled[t] = -INFINITY;
}

__device__ __forceinline__ void atomicMaxFloat(float* addr, float value) {
    if (value >= 0.0f)
        atomicMax((int*)addr, __float_as_int(value));
    else
        atomicMin((unsigned int*)addr, (unsigned int)__float_as_int(value));
}

__global__ void pool_max(float* __restrict__ pooled, const float* __restrict__ h,
                         const int* __restrict__ batch, int n_nodes) {
    int lane = threadIdx.x & 63;
    int wave = (blockIdx.x * blockDim.x + threadIdx.x) >> 6;
    int nwaves = (gridDim.x * blockDim.x) >> 6;
    for (int i = wave; i < n_nodes; i += nwaves) {
        int g = batch[i];
        float v = h[(size_t)i * 64 + lane];
        atomicMaxFloat(&pooled[(size_t)g * 64 + lane], v);
    }
}

// ---------------- MLP head ----------------
// 128 graphs, wave per graph. g = tanh(g@W1.T+b1) x3, then out = g@W2.T+b2
__global__ void head(float* __restrict__ out, const float* __restrict__ pooled,
                     const float* __restrict__ W1, const float* __restrict__ b1,
                     const float* __restrict__ W2, const float* __restrict__ b2) {
    __shared__ float W1T[64][64];
    int tid = threadIdx.x;
    for (int t = tid; t < 4096; t += blockDim.x) {
        int f = t >> 6, k = t & 63;
        W1T[k][f] = W1[t];
    }
    __syncthreads();

    int lane = tid & 63;
    int g = blockIdx.x * (blockDim.x >> 6) + (tid >> 6);  // 32 blocks * 4 waves = 128
    float v = pooled[(size_t)g * 64 + lane];
    float bias = b1[lane];
#pragma unroll
    for (int it = 0; it < 3; ++it) {
        float acc = bias;
#pragma unroll
        for (int k = 0; k < 64; ++k) {
            acc += __shfl(v, k) * W1T[k][lane];
        }
        v = tanhf(acc);
    }
#pragma unroll
    for (int j = 0; j < 3; ++j) {
        float p = v * W2[j * 64 + lane];
#pragma unroll
        for (int off = 32; off >= 1; off >>= 1) p += __shfl_xor(p, off);
        if (lane == 0) out[g * 3 + j] = p + b2[j];
    }
}

// ---------------- launch ----------------

extern "C" void kernel_launch(void* const* d_in, const int* in_sizes, int n_in,
                              void* d_out, int out_size, void* d_ws, size_t ws_size,
                              hipStream_t stream) {
    const float* x   = (const float*)d_in[0];
    const float* Wl0 = (const float*)d_in[1];
    const float* Wr0 = (const float*)d_in[2];
    const float* bl0 = (const float*)d_in[3];
    const float* Wl  = (const float*)d_in[4];
    const float* Wr  = (const float*)d_in[5];
    const float* bl  = (const float*)d_in[6];
    const float* W1  = (const float*)d_in[7];
    const float* b1  = (const float*)d_in[8];
    const float* W2  = (const float*)d_in[9];
    const float* b2  = (const float*)d_in[10];
    const int* ei    = (const int*)d_in[11];
    const int* batch = (const int*)d_in[12];

    int n_nodes = in_sizes[0] / 64;
    int n_edges = in_sizes[11] / 2;
    const int* src = ei;
    const int* dst = ei + n_edges;

    float* bufA   = (float*)d_ws;                       // n_nodes*64
    float* bufB   = bufA + (size_t)n_nodes * 64;        // n_nodes*64
    float* invdeg = bufB + (size_t)n_nodes * 64;        // n_nodes
    float* pooled = invdeg + n_nodes;                   // 128*64

    const int nblk = 2048;

    // degree -> invdeg (same for all 4 layers)
    zero_f32<<<256, NT, 0, stream>>>(invdeg, n_nodes);
    deg_count<<<nblk, NT, 0, stream>>>(invdeg, dst, n_edges);
    deg_inv<<<(n_nodes + NT - 1) / NT, NT, 0, stream>>>(invdeg, n_nodes);

    // layer 0: x -> bufA
    zero_f32<<<nblk, NT, 0, stream>>>(bufA, n_nodes * 64);
    scatter_add<<<nblk, NT, 0, stream>>>(bufA, x, src, dst, n_edges);
    sage_update<<<nblk, NT, 0, stream>>>(bufA, x, Wl0, Wr0, bl0, invdeg, n_nodes);

    // layers 1..3 (shared weights), ping-pong
    float* h_in = bufA;
    float* h_out = bufB;
    for (int l = 0; l < 3; ++l) {
        zero_f32<<<nblk, NT, 0, stream>>>(h_out, n_nodes * 64);
        scatter_add<<<nblk, NT, 0, stream>>>(h_out, h_in, src, dst, n_edges);
        sage_update<<<nblk, NT, 0, stream>>>(h_out, h_in, Wl, Wr, bl, invdeg, n_nodes);
        float* t = h_in; h_in = h_out; h_out = t;
    }
    // final h is in h_in

    pool_init<<<(128 * 64 + NT - 1) / NT, NT, 0, stream>>>(pooled, 128 * 64);
    pool_max<<<nblk, NT, 0, stream>>>(pooled, h_in, batch, n_nodes);
    head<<<32, NT, 0, stream>>>((float*)d_out, pooled, W1, b1, W2, b2);
}

// Round 2
// 1343.541 us; speedup vs baseline: 1.0693x; 1.0693x over previous
//
#include <hip/hip_runtime.h>
#include <math.h>

#define NT 256

// ---------------- CSR build ----------------

__global__ void zero_i32(int* __restrict__ p, int n) {
    int t = blockIdx.x * blockDim.x + threadIdx.x;
    if (t < n) p[t] = 0;
}

__global__ void hist_dst(int* __restrict__ cnt, const int* __restrict__ dst, int n_edges) {
    int e = blockIdx.x * blockDim.x + threadIdx.x;
    if (e < n_edges) atomicAdd(&cnt[dst[e]], 1);
}

// single-block exclusive scan of cnt[0..n) -> row_off[0..n], cursor[0..n)
__global__ void scan_offsets(const int* __restrict__ cnt, int* __restrict__ row_off,
                             int* __restrict__ cursor, int n) {
    __shared__ int tsum[1024];
    int tid = threadIdx.x;
    int chunk = (n + 1023) / 1024;
    int beg = tid * chunk;
    int end = beg + chunk; if (end > n) end = n;
    int s = 0;
    for (int i = beg; i < end; ++i) s += cnt[i];
    tsum[tid] = s;
    __syncthreads();
    for (int off = 1; off < 1024; off <<= 1) {
        int v = (tid >= off) ? tsum[tid - off] : 0;
        __syncthreads();
        tsum[tid] += v;
        __syncthreads();
    }
    int run = (tid == 0) ? 0 : tsum[tid - 1];  // exclusive prefix of this thread's chunk
    for (int i = beg; i < end; ++i) {
        row_off[i] = run;
        cursor[i] = run;
        run += cnt[i];
    }
    if (tid == 1023) row_off[n] = tsum[1023];
}

__global__ void edge_scatter(int* __restrict__ csr_src, int* __restrict__ cursor,
                             const int* __restrict__ src, const int* __restrict__ dst,
                             int n_edges) {
    int e = blockIdx.x * blockDim.x + threadIdx.x;
    if (e < n_edges) {
        int p = atomicAdd(&cursor[dst[e]], 1);
        csr_src[p] = src[e];
    }
}

// ---------------- pooling helpers ----------------

__global__ void pool_init(float* __restrict__ pooled, int n) {
    int t = blockIdx.x * blockDim.x + threadIdx.x;
    if (t < n) pooled[t] = -INFINITY;
}

__device__ __forceinline__ void atomicMaxFloat(float* addr, float value) {
    if (value >= 0.0f)
        atomicMax((int*)addr, __float_as_int(value));
    else
        atomicMin((unsigned int*)addr, (unsigned int)__float_as_int(value));
}

// ---------------- fused SAGE layer: gather-mean + dense + tanh (+ optional pool) ----
// wave per node, lane = feature.
__global__ __launch_bounds__(NT) void sage_layer(
    float* __restrict__ out, float* __restrict__ pooled,
    const float* __restrict__ h_in,
    const int* __restrict__ row_off, const int* __restrict__ csr_src,
    const int* __restrict__ batch,
    const float* __restrict__ Wl, const float* __restrict__ Wr,
    const float* __restrict__ bl,
    int n_nodes, int do_pool) {
    __shared__ float WlT[64][64];  // WlT[k][f] = Wl[f][k]
    __shared__ float WrT[64][64];
    int tid = threadIdx.x;
    for (int t = tid; t < 4096; t += NT) {
        int f = t >> 6, k = t & 63;
        WlT[k][f] = Wl[t];
        WrT[k][f] = Wr[t];
    }
    __syncthreads();

    int lane = tid & 63;
    int i = (blockIdx.x * NT + tid) >> 6;
    if (i >= n_nodes) return;

    int beg = row_off[i];
    int end = row_off[i + 1];
    int cnt = end - beg;
    float invd = 1.0f / (float)(cnt > 0 ? cnt : 1);

    // gather-accumulate mean over neighbors
    float acc = 0.0f;
    int e = beg;
    while (e < end) {
        int m = end - e; if (m > 64) m = 64;
        int le = e + lane; if (le > end - 1) le = end - 1;
        int idx = csr_src[le];  // coalesced index block
        int k = 0;
        for (; k + 4 <= m; k += 4) {
            int s0 = __shfl(idx, k);
            int s1 = __shfl(idx, k + 1);
            int s2 = __shfl(idx, k + 2);
            int s3 = __shfl(idx, k + 3);
            float v0 = h_in[(size_t)s0 * 64 + lane];
            float v1 = h_in[(size_t)s1 * 64 + lane];
            float v2 = h_in[(size_t)s2 * 64 + lane];
            float v3 = h_in[(size_t)s3 * 64 + lane];
            acc += v0 + v1 + v2 + v3;
        }
        for (; k < m; ++k)
            acc += h_in[(size_t)__shfl(idx, k) * 64 + lane];
        e += m;
    }
    float mean = acc * invd;
    float hv = h_in[(size_t)i * 64 + lane];

    float o = bl[lane];
#pragma unroll
    for (int k = 0; k < 64; ++k) {
        o += __shfl(mean, k) * WlT[k][lane] + __shfl(hv, k) * WrT[k][lane];
    }
    o = tanhf(o);

    if (do_pool) {
        int g = batch[i];
        atomicMaxFloat(&pooled[(size_t)g * 64 + lane], o);
    } else {
        out[(size_t)i * 64 + lane] = o;
    }
}

// ---------------- MLP head ----------------
__global__ void head(float* __restrict__ out, const float* __restrict__ pooled,
                     const float* __restrict__ W1, const float* __restrict__ b1,
                     const float* __restrict__ W2, const float* __restrict__ b2) {
    __shared__ float W1T[64][64];
    int tid = threadIdx.x;
    for (int t = tid; t < 4096; t += NT) {
        int f = t >> 6, k = t & 63;
        W1T[k][f] = W1[t];
    }
    __syncthreads();

    int lane = tid & 63;
    int g = blockIdx.x * (NT >> 6) + (tid >> 6);  // 32 blocks * 4 waves = 128
    float v = pooled[(size_t)g * 64 + lane];
    float bias = b1[lane];
#pragma unroll
    for (int it = 0; it < 3; ++it) {
        float acc = bias;
#pragma unroll
        for (int k = 0; k < 64; ++k) {
            acc += __shfl(v, k) * W1T[k][lane];
        }
        v = tanhf(acc);
    }
#pragma unroll
    for (int j = 0; j < 3; ++j) {
        float p = v * W2[j * 64 + lane];
#pragma unroll
        for (int off = 32; off >= 1; off >>= 1) p += __shfl_xor(p, off);
        if (lane == 0) out[g * 3 + j] = p + b2[j];
    }
}

// ---------------- launch ----------------

extern "C" void kernel_launch(void* const* d_in, const int* in_sizes, int n_in,
                              void* d_out, int out_size, void* d_ws, size_t ws_size,
                              hipStream_t stream) {
    const float* x   = (const float*)d_in[0];
    const float* Wl0 = (const float*)d_in[1];
    const float* Wr0 = (const float*)d_in[2];
    const float* bl0 = (const float*)d_in[3];
    const float* Wl  = (const float*)d_in[4];
    const float* Wr  = (const float*)d_in[5];
    const float* bl  = (const float*)d_in[6];
    const float* W1  = (const float*)d_in[7];
    const float* b1  = (const float*)d_in[8];
    const float* W2  = (const float*)d_in[9];
    const float* b2  = (const float*)d_in[10];
    const int* ei    = (const int*)d_in[11];
    const int* batch = (const int*)d_in[12];

    int n_nodes = in_sizes[0] / 64;
    int n_edges = in_sizes[11] / 2;
    const int* src = ei;
    const int* dst = ei + n_edges;

    // workspace layout
    float* bufA   = (float*)d_ws;                         // n_nodes*64
    float* bufB   = bufA + (size_t)n_nodes * 64;          // n_nodes*64
    int* csr_src  = (int*)(bufB + (size_t)n_nodes * 64);  // n_edges
    int* row_off  = csr_src + n_edges;                    // n_nodes+1
    int* cursor   = row_off + (n_nodes + 1);              // n_nodes
    int* cnt      = cursor + n_nodes;                     // n_nodes
    float* pooled = (float*)(cnt + n_nodes);              // 128*64

    int eblk = (n_edges + NT - 1) / NT;
    int nblk = (n_nodes + NT - 1) / NT;
    int lblk = (n_nodes * 64 + NT * 64 - 1) / (NT * 64) * 64;  // waves cover nodes
    lblk = (n_nodes + (NT / 64) - 1) / (NT / 64);

    // CSR build
    zero_i32<<<nblk, NT, 0, stream>>>(cnt, n_nodes);
    hist_dst<<<eblk, NT, 0, stream>>>(cnt, dst, n_edges);
    scan_offsets<<<1, 1024, 0, stream>>>(cnt, row_off, cursor, n_nodes);
    edge_scatter<<<eblk, NT, 0, stream>>>(csr_src, cursor, src, dst, n_edges);

    pool_init<<<(128 * 64 + NT - 1) / NT, NT, 0, stream>>>(pooled, 128 * 64);

    // layer 0: x -> bufA
    sage_layer<<<lblk, NT, 0, stream>>>(bufA, pooled, x, row_off, csr_src, batch,
                                        Wl0, Wr0, bl0, n_nodes, 0);
    // layers 1..2: shared weights, ping-pong
    sage_layer<<<lblk, NT, 0, stream>>>(bufB, pooled, bufA, row_off, csr_src, batch,
                                        Wl, Wr, bl, n_nodes, 0);
    sage_layer<<<lblk, NT, 0, stream>>>(bufA, pooled, bufB, row_off, csr_src, batch,
                                        Wl, Wr, bl, n_nodes, 0);
    // layer 3: fused segment-max pooling
    sage_layer<<<lblk, NT, 0, stream>>>(bufB, pooled, bufA, row_off, csr_src, batch,
                                        Wl, Wr, bl, n_nodes, 1);

    head<<<32, NT, 0, stream>>>((float*)d_out, pooled, W1, b1, W2, b2);
}

// Round 4
// 591.625 us; speedup vs baseline: 2.4283x; 2.2709x over previous
//
#include <hip/hip_runtime.h>
#include <math.h>

#define NT 256

__device__ __forceinline__ float rlf(float v, int l) {
    return __int_as_float(__builtin_amdgcn_readlane(__float_as_int(v), l));
}
__device__ __forceinline__ int rli(int v, int l) {
    return __builtin_amdgcn_readlane(v, l);
}

// ---------------- CSR build ----------------

__global__ void zero_i32(int* __restrict__ p, int n) {
    int t = blockIdx.x * blockDim.x + threadIdx.x;
    if (t < n) p[t] = 0;
}

__global__ void hist_dst(int* __restrict__ cnt, const int* __restrict__ dst, int n_edges) {
    int e = blockIdx.x * blockDim.x + threadIdx.x;
    if (e < n_edges) atomicAdd(&cnt[dst[e]], 1);
}

// single-block exclusive scan of cnt[0..n) -> row_off[0..n], cursor[0..n)
__global__ void scan_offsets(const int* __restrict__ cnt, int* __restrict__ row_off,
                             int* __restrict__ cursor, int n) {
    __shared__ int tsum[1024];
    int tid = threadIdx.x;
    int chunk = (n + 1023) / 1024;
    int beg = tid * chunk;
    int end = beg + chunk; if (end > n) end = n;
    int s = 0;
    for (int i = beg; i < end; ++i) s += cnt[i];
    tsum[tid] = s;
    __syncthreads();
    for (int off = 1; off < 1024; off <<= 1) {
        int v = (tid >= off) ? tsum[tid - off] : 0;
        __syncthreads();
        tsum[tid] += v;
        __syncthreads();
    }
    int run = (tid == 0) ? 0 : tsum[tid - 1];
    for (int i = beg; i < end; ++i) {
        row_off[i] = run;
        cursor[i] = run;
        run += cnt[i];
    }
    if (tid == 1023) row_off[n] = tsum[1023];
}

__global__ void edge_scatter(int* __restrict__ csr_src, int* __restrict__ cursor,
                             const int* __restrict__ src, const int* __restrict__ dst,
                             int n_edges) {
    int e = blockIdx.x * blockDim.x + threadIdx.x;
    if (e < n_edges) {
        int p = atomicAdd(&cursor[dst[e]], 1);
        csr_src[p] = src[e];
    }
}

// ---------------- pooling helpers ----------------

__global__ void pool_init(float* __restrict__ pooled, int n) {
    int t = blockIdx.x * blockDim.x + threadIdx.x;
    if (t < n) pooled[t] = -INFINITY;
}

__device__ __forceinline__ void atomicMaxFloat(float* addr, float value) {
    if (value >= 0.0f)
        atomicMax((int*)addr, __float_as_int(value));
    else
        atomicMin((unsigned int*)addr, (unsigned int)__float_as_int(value));
}

// ---------------- fused SAGE layer ----------------
// Persistent waves; each wave processes 4 nodes per iteration.
// Gather: neighbor indices loaded coalesced once, broadcast via v_readlane,
// gathers issued 8-wide with SGPR base. Dense: weights in LDS [k4][lane][4]
// (conflict-free ds_read_b128), multiplier broadcast via v_readlane.
__global__ __launch_bounds__(NT, 4) void sage_layer(
    float* __restrict__ out, float* __restrict__ pooled,
    const float* __restrict__ h_in,
    const int* __restrict__ row_off, const int* __restrict__ csr_src,
    const int* __restrict__ batch,
    const float* __restrict__ Wl, const float* __restrict__ Wr,
    const float* __restrict__ bl,
    int n_nodes, int do_pool) {
    __shared__ float WL[4096];  // WL[k4*256 + f*4 + kk] = Wl[f][k4*4+kk]
    __shared__ float WR[4096];
    int tid = threadIdx.x;
    for (int t = tid; t < 4096; t += NT) {
        int kk = t & 3, f = (t >> 2) & 63, k4 = t >> 8;
        WL[t] = Wl[f * 64 + k4 * 4 + kk];
        WR[t] = Wr[f * 64 + k4 * 4 + kk];
    }
    __syncthreads();

    int lane = tid & 63;
    int gwave = (blockIdx.x * NT + tid) >> 6;
    int nwaves = (gridDim.x * NT) >> 6;
    float bias = bl[lane];

    for (int q = gwave; q * 4 < n_nodes; q += nwaves) {
        int base = q * 4;
        float mean0 = 0.f, mean1 = 0.f, mean2 = 0.f, mean3 = 0.f;
        float hv0 = 0.f, hv1 = 0.f, hv2 = 0.f, hv3 = 0.f;

#define GATHER_NODE(MEAN, HV, N)                                              \
        {                                                                     \
            int i = base + (N);                                               \
            if (i < n_nodes) {                                                \
                int beg = row_off[i];                                         \
                int end_ = row_off[i + 1];                                    \
                int deg = end_ - beg;                                         \
                float a0 = 0.f, a1 = 0.f;                                     \
                for (int cb = beg; cb < end_; cb += 64) {                     \
                    int m = end_ - cb; if (m > 64) m = 64;                    \
                    int lidx = cb + (lane < m ? lane : m - 1);                \
                    int idx = csr_src[lidx];                                  \
                    for (int j = 0; j < m; j += 8) {                          \
                        int mm1 = m - 1;                                      \
                        int s0 = rli(idx, j);                                 \
                        int s1 = rli(idx, j + 1 < m ? j + 1 : mm1);           \
                        int s2 = rli(idx, j + 2 < m ? j + 2 : mm1);           \
                        int s3 = rli(idx, j + 3 < m ? j + 3 : mm1);           \
                        int s4 = rli(idx, j + 4 < m ? j + 4 : mm1);           \
                        int s5 = rli(idx, j + 5 < m ? j + 5 : mm1);           \
                        int s6 = rli(idx, j + 6 < m ? j + 6 : mm1);           \
                        int s7 = rli(idx, j + 7 < m ? j + 7 : mm1);           \
                        float v0 = h_in[s0 * 64 + lane];                      \
                        float v1 = h_in[s1 * 64 + lane];                      \
                        float v2 = h_in[s2 * 64 + lane];                      \
                        float v3 = h_in[s3 * 64 + lane];                      \
                        float v4 = h_in[s4 * 64 + lane];                      \
                        float v5 = h_in[s5 * 64 + lane];                      \
                        float v6 = h_in[s6 * 64 + lane];                      \
                        float v7 = h_in[s7 * 64 + lane];                      \
                        a0 += v0;                                             \
                        a1 += (j + 1 < m) ? v1 : 0.f;                         \
                        a0 += (j + 2 < m) ? v2 : 0.f;                         \
                        a1 += (j + 3 < m) ? v3 : 0.f;                         \
                        a0 += (j + 4 < m) ? v4 : 0.f;                         \
                        a1 += (j + 5 < m) ? v5 : 0.f;                         \
                        a0 += (j + 6 < m) ? v6 : 0.f;                         \
                        a1 += (j + 7 < m) ? v7 : 0.f;                         \
                    }                                                         \
                }                                                             \
                MEAN = (a0 + a1) * (1.0f / (float)(deg > 0 ? deg : 1));       \
                HV = h_in[i * 64 + lane];                                     \
            }                                                                 \
        }

        GATHER_NODE(mean0, hv0, 0)
        GATHER_NODE(mean1, hv1, 1)
        GATHER_NODE(mean2, hv2, 2)
        GATHER_NODE(mean3, hv3, 3)
#undef GATHER_NODE

        float o0 = bias, o1 = bias, o2 = bias, o3 = bias;
        for (int k4 = 0; k4 < 16; ++k4) {
            float4 wl = *(const float4*)&WL[k4 * 256 + lane * 4];
            float4 wr = *(const float4*)&WR[k4 * 256 + lane * 4];
            int kb = k4 * 4;
#define DENSE_KK(WLK, WRK, KK)                                                \
            {                                                                 \
                int k = kb + (KK);                                            \
                o0 += rlf(mean0, k) * (WLK) + rlf(hv0, k) * (WRK);            \
                o1 += rlf(mean1, k) * (WLK) + rlf(hv1, k) * (WRK);            \
                o2 += rlf(mean2, k) * (WLK) + rlf(hv2, k) * (WRK);            \
                o3 += rlf(mean3, k) * (WLK) + rlf(hv3, k) * (WRK);            \
            }
            DENSE_KK(wl.x, wr.x, 0)
            DENSE_KK(wl.y, wr.y, 1)
            DENSE_KK(wl.z, wr.z, 2)
            DENSE_KK(wl.w, wr.w, 3)
#undef DENSE_KK
        }

        o0 = tanhf(o0); o1 = tanhf(o1); o2 = tanhf(o2); o3 = tanhf(o3);

#define WRITE_NODE(O, N)                                                      \
        {                                                                     \
            int i = base + (N);                                               \
            if (i < n_nodes) {                                                \
                if (do_pool) {                                                \
                    atomicMaxFloat(&pooled[(size_t)batch[i] * 64 + lane], O); \
                } else {                                                      \
                    out[(size_t)i * 64 + lane] = O;                           \
                }                                                             \
            }                                                                 \
        }
        WRITE_NODE(o0, 0)
        WRITE_NODE(o1, 1)
        WRITE_NODE(o2, 2)
        WRITE_NODE(o3, 3)
#undef WRITE_NODE
    }
}

// ---------------- MLP head ----------------
__global__ void head(float* __restrict__ out, const float* __restrict__ pooled,
                     const float* __restrict__ W1, const float* __restrict__ b1,
                     const float* __restrict__ W2, const float* __restrict__ b2) {
    __shared__ float W1T[64][64];
    int tid = threadIdx.x;
    for (int t = tid; t < 4096; t += NT) {
        int f = t >> 6, k = t & 63;
        W1T[k][f] = W1[t];
    }
    __syncthreads();

    int lane = tid & 63;
    int g = blockIdx.x * (NT >> 6) + (tid >> 6);
    float v = pooled[(size_t)g * 64 + lane];
    float bias = b1[lane];
#pragma unroll
    for (int it = 0; it < 3; ++it) {
        float acc = bias;
#pragma unroll
        for (int k = 0; k < 64; ++k) {
            acc += rlf(v, k) * W1T[k][lane];
        }
        v = tanhf(acc);
    }
#pragma unroll
    for (int j = 0; j < 3; ++j) {
        float p = v * W2[j * 64 + lane];
#pragma unroll
        for (int off = 32; off >= 1; off >>= 1) p += __shfl_xor(p, off);
        if (lane == 0) out[g * 3 + j] = p + b2[j];
    }
}

// ---------------- launch ----------------

extern "C" void kernel_launch(void* const* d_in, const int* in_sizes, int n_in,
                              void* d_out, int out_size, void* d_ws, size_t ws_size,
                              hipStream_t stream) {
    const float* x   = (const float*)d_in[0];
    const float* Wl0 = (const float*)d_in[1];
    const float* Wr0 = (const float*)d_in[2];
    const float* bl0 = (const float*)d_in[3];
    const float* Wl  = (const float*)d_in[4];
    const float* Wr  = (const float*)d_in[5];
    const float* bl  = (const float*)d_in[6];
    const float* W1  = (const float*)d_in[7];
    const float* b1  = (const float*)d_in[8];
    const float* W2  = (const float*)d_in[9];
    const float* b2  = (const float*)d_in[10];
    const int* ei    = (const int*)d_in[11];
    const int* batch = (const int*)d_in[12];

    int n_nodes = in_sizes[0] / 64;
    int n_edges = in_sizes[11] / 2;
    const int* src = ei;
    const int* dst = ei + n_edges;

    float* bufA   = (float*)d_ws;                         // n_nodes*64
    float* bufB   = bufA + (size_t)n_nodes * 64;          // n_nodes*64
    int* csr_src  = (int*)(bufB + (size_t)n_nodes * 64);  // n_edges
    int* row_off  = csr_src + n_edges;                    // n_nodes+1
    int* cursor   = row_off + (n_nodes + 1);              // n_nodes
    int* cnt      = cursor + n_nodes;                     // n_nodes
    float* pooled = (float*)(cnt + n_nodes);              // 128*64

    int eblk = (n_edges + NT - 1) / NT;
    int nblk = (n_nodes + NT - 1) / NT;
    const int pers_blk = 1024;

    // CSR build
    zero_i32<<<nblk, NT, 0, stream>>>(cnt, n_nodes);
    hist_dst<<<eblk, NT, 0, stream>>>(cnt, dst, n_edges);
    scan_offsets<<<1, 1024, 0, stream>>>(cnt, row_off, cursor, n_nodes);
    edge_scatter<<<eblk, NT, 0, stream>>>(csr_src, cursor, src, dst, n_edges);

    pool_init<<<(128 * 64 + NT - 1) / NT, NT, 0, stream>>>(pooled, 128 * 64);

    sage_layer<<<pers_blk, NT, 0, stream>>>(bufA, pooled, x, row_off, csr_src, batch,
                                            Wl0, Wr0, bl0, n_nodes, 0);
    sage_layer<<<pers_blk, NT, 0, stream>>>(bufB, pooled, bufA, row_off, csr_src, batch,
                                            Wl, Wr, bl, n_nodes, 0);
    sage_layer<<<pers_blk, NT, 0, stream>>>(bufA, pooled, bufB, row_off, csr_src, batch,
                                            Wl, Wr, bl, n_nodes, 0);
    sage_layer<<<pers_blk, NT, 0, stream>>>(bufB, pooled, bufA, row_off, csr_src, batch,
                                            Wl, Wr, bl, n_nodes, 1);

    head<<<32, NT, 0, stream>>>((float*)d_out, pooled, W1, b1, W2, b2);
}